// Round 3
// baseline (460.795 us; speedup 1.0000x reference)
//
#include <hip/hip_runtime.h>
#include <stdint.h>

typedef unsigned short u16;

#define B_ROWS 8192
#define IN_DIM 4096
#define MEM 256
#define D_IN 4352   // MEM + IN_DIM
#define N1 1024     // 512 | 256 | 256
#define K2 512
#define LN_EPS 1e-5f

typedef __attribute__((ext_vector_type(4))) float f32x4;
typedef __attribute__((ext_vector_type(4))) uint32_t u32x4;
typedef __attribute__((ext_vector_type(8))) short bf16x8;  // 8 bf16 in 4 VGPRs

#define AS1(p) ((__attribute__((address_space(1))) void*)(p))
#define AS3(p) ((__attribute__((address_space(3))) void*)(p))

__device__ __forceinline__ float bf2f(u16 u) {
  union { uint32_t u; float f; } c; c.u = ((uint32_t)u) << 16; return c.f;
}
__device__ __forceinline__ u16 f2bf(float f) {  // round-to-nearest-even
  union { float f; uint32_t u; } c; c.f = f;
  uint32_t r = (c.u + 0x7fffu + ((c.u >> 16) & 1u)) >> 16;
  return (u16)r;
}
__device__ __forceinline__ uint32_t fbits(float f) {
  union { float f; uint32_t u; } c; c.f = f; return c.u;
}
// pack bf16(b)<<16 | bf16(a), truncation (cheap; error ok at 0.325 threshold)
__device__ __forceinline__ uint32_t pack_trunc(float a, float b) {
  return (fbits(b) & 0xFFFF0000u) | (fbits(a) >> 16);
}

// -------- weight transpose+cast: src[K][N] fp32 -> dst[N][K] bf16 --------
__global__ void transpose_cast(const float* __restrict__ src, u16* __restrict__ dst,
                               int K, int N) {
  __shared__ u16 tile[32][34];
  int n0 = blockIdx.x * 32, k0 = blockIdx.y * 32;
  int tx = threadIdx.x, ty = threadIdx.y;  // (32, 8)
#pragma unroll
  for (int i = 0; i < 4; i++)
    tile[ty + i * 8][tx] = f2bf(src[(size_t)(k0 + ty + i * 8) * N + n0 + tx]);
  __syncthreads();
#pragma unroll
  for (int i = 0; i < 4; i++)
    dst[(size_t)(n0 + ty + i * 8) * K + k0 + tx] = tile[tx][ty + i * 8];
}

// -------- GEMM1: [h|x](fp32) @ WT^T(bf16) -> G bf16 [8192][1024] --------
// 128x128 tile, BK=64, 256 threads = 4 waves (2x2), 16x16x32 bf16 MFMA.
// A staged via fp32 loads + truncate-cast + ds_write; B via global_load_lds.
__global__ __launch_bounds__(256, 2)
void gemm1_kernel(const float* __restrict__ x, const float* __restrict__ h,
                  const u16* __restrict__ WT, u16* __restrict__ G) {
  __shared__ __attribute__((aligned(16))) u16 As[128 * 64];
  __shared__ __attribute__((aligned(16))) u16 Bs[128 * 64];
  const int t = threadIdx.x;
  const int lane = t & 63, wave = t >> 6;
  const int bx = blockIdx.x & 7;   // N tile (8) -> XCD-pinned
  const int by = blockIdx.x >> 3;  // M tile (64)
  const int row0 = by * 128, col0 = bx * 128;
  const int q = lane >> 4, mrow = lane & 15;
  const int wm = wave >> 1, wn = wave & 1;

  int ar[4], ac[4];  // staging: row, (xor-swizzled) chunk col
#pragma unroll
  for (int j = 0; j < 4; j++) {
    int idx = j * 256 + t;
    int r = idx >> 3;
    ar[j] = r;
    ac[j] = (idx & 7) ^ (r & 7);
  }

  f32x4 acc[4][4] = {};

  for (int k0 = 0; k0 < D_IN; k0 += 64) {
    // B tile: async DMA, bf16 weights
#pragma unroll
    for (int j = 0; j < 4; j++) {
      const u16* gp = WT + (size_t)(col0 + ar[j]) * D_IN + k0 + ac[j] * 8;
      __builtin_amdgcn_global_load_lds(AS1(gp), AS3(&Bs[(j * 256 + t) * 8]), 16, 0, 0);
    }
    // A tile: fp32 -> bf16 cast during staging (prev iter's readers done at loop-tail sync)
#pragma unroll
    for (int j = 0; j < 4; j++) {
      int k = k0 + ac[j] * 8;
      const float* gp = (k < MEM) ? (h + (size_t)(row0 + ar[j]) * MEM + k)
                                  : (x + (size_t)(row0 + ar[j]) * IN_DIM + (k - MEM));
      f32x4 v0 = *(const f32x4*)gp;
      f32x4 v1 = *(const f32x4*)(gp + 4);
      u32x4 w;
      w.x = pack_trunc(v0[0], v0[1]);
      w.y = pack_trunc(v0[2], v0[3]);
      w.z = pack_trunc(v1[0], v1[1]);
      w.w = pack_trunc(v1[2], v1[3]);
      *(u32x4*)&As[(j * 256 + t) * 8] = w;
    }
    __syncthreads();
#pragma unroll
    for (int kk = 0; kk < 2; kk++) {
      bf16x8 a[4], b[4];
#pragma unroll
      for (int mt = 0; mt < 4; mt++) {
        int row = wm * 64 + mt * 16 + mrow;
        int p = (kk * 4 + q) ^ (mrow & 7);
        a[mt] = *(const bf16x8*)&As[row * 64 + p * 8];
      }
#pragma unroll
      for (int nt = 0; nt < 4; nt++) {
        int row = wn * 64 + nt * 16 + mrow;
        int p = (kk * 4 + q) ^ (mrow & 7);
        b[nt] = *(const bf16x8*)&Bs[row * 64 + p * 8];
      }
#pragma unroll
      for (int mt = 0; mt < 4; mt++) {
#pragma unroll
        for (int nt = 0; nt < 4; nt++) {
          acc[mt][nt] = __builtin_amdgcn_mfma_f32_16x16x32_bf16(a[mt], b[nt], acc[mt][nt], 0, 0, 0);
        }
      }
    }
    __syncthreads();
  }
  // C/D layout: col=lane&15, row=(lane>>4)*4+reg  [m89-verified]
#pragma unroll
  for (int mt = 0; mt < 4; mt++) {
#pragma unroll
    for (int nt = 0; nt < 4; nt++) {
#pragma unroll
      for (int i = 0; i < 4; i++) {
        int row = row0 + wm * 64 + mt * 16 + q * 4 + i;
        int col = col0 + wn * 64 + nt * 16 + mrow;
        G[(size_t)row * N1 + col] = f2bf(acc[mt][nt][i]);
      }
    }
  }
}

// -------- LN + exact GELU, IN PLACE on G[:, :512] (biases fp32) --------
__global__ __launch_bounds__(256)
void ln_gelu_kernel(u16* __restrict__ G, const float* __restrict__ b1,
                    const float* __restrict__ g1, const float* __restrict__ be1) {
  int r = blockIdx.x;
  int t = threadIdx.x;
  u16* row = G + (size_t)r * N1;
  float z0 = bf2f(row[t]) + b1[t];
  float z1 = bf2f(row[t + 256]) + b1[t + 256];
  float s = z0 + z1, ss = z0 * z0 + z1 * z1;
#pragma unroll
  for (int m = 32; m >= 1; m >>= 1) {
    s += __shfl_xor(s, m, 64);
    ss += __shfl_xor(ss, m, 64);
  }
  __shared__ float rs[4], rss[4];
  int lane = t & 63, wave = t >> 6;
  if (lane == 0) { rs[wave] = s; rss[wave] = ss; }
  __syncthreads();
  float S = rs[0] + rs[1] + rs[2] + rs[3];
  float SS = rss[0] + rss[1] + rss[2] + rss[3];
  float mu = S * (1.0f / 512.0f);
  float var = SS * (1.0f / 512.0f) - mu * mu;
  float rstd = rsqrtf(var + LN_EPS);
  float y0 = (z0 - mu) * rstd * g1[t] + be1[t];
  float y1 = (z1 - mu) * rstd * g1[t + 256] + be1[t + 256];
  float o0 = 0.5f * y0 * (1.0f + erff(y0 * 0.7071067811865475f));
  float o1 = 0.5f * y1 * (1.0f + erff(y1 * 0.7071067811865475f));
  row[t] = f2bf(o0);
  row[t + 256] = f2bf(o1);
}

// -------- GEMM2 + full epilogue -> out fp32 [8192][256] --------
// 32x256 tile (full output width), BK=64, 4 waves side-by-side in N.
// A = G[:, 0:512] (post LN+GELU, bf16), gates from G[:, 512:1024].
__global__ __launch_bounds__(256, 2)
void gemm2_epi_kernel(const u16* __restrict__ G, const u16* __restrict__ W2T,
                      const float* __restrict__ h,
                      const float* __restrict__ b2, const float* __restrict__ bd,
                      const float* __restrict__ bu, float* __restrict__ out) {
  __shared__ __attribute__((aligned(16))) u16 As[32 * 64];
  __shared__ __attribute__((aligned(16))) u16 Bs[256 * 64];
  __shared__ float red_nh[32][4], red_h[32][4], scl[32];
  const int t = threadIdx.x, lane = t & 63, wave = t >> 6;
  const int q = lane >> 4, mrow = lane & 15;
  const int r0 = blockIdx.x * 32;

  const int arA = t >> 3;
  const int acA = (t & 7) ^ (arA & 7);
  int brB[8], bcB[8];
#pragma unroll
  for (int j = 0; j < 8; j++) {
    int idx = j * 256 + t;
    brB[j] = idx >> 3;
    bcB[j] = (idx & 7) ^ (brB[j] & 7);
  }
  f32x4 acc[2][4] = {};
  for (int k0 = 0; k0 < K2; k0 += 64) {
    __builtin_amdgcn_global_load_lds(AS1(G + (size_t)(r0 + arA) * N1 + k0 + acA * 8),
                                     AS3(&As[t * 8]), 16, 0, 0);
#pragma unroll
    for (int j = 0; j < 8; j++) {
      __builtin_amdgcn_global_load_lds(AS1(W2T + (size_t)brB[j] * K2 + k0 + bcB[j] * 8),
                                       AS3(&Bs[(j * 256 + t) * 8]), 16, 0, 0);
    }
    __syncthreads();
#pragma unroll
    for (int kk = 0; kk < 2; kk++) {
      bf16x8 a[2], b[4];
#pragma unroll
      for (int mt = 0; mt < 2; mt++) {
        int row = mt * 16 + mrow;
        int p = (kk * 4 + q) ^ (row & 7);
        a[mt] = *(const bf16x8*)&As[row * 64 + p * 8];
      }
#pragma unroll
      for (int nt = 0; nt < 4; nt++) {
        int row = wave * 64 + nt * 16 + mrow;
        int p = (kk * 4 + q) ^ (row & 7);
        b[nt] = *(const bf16x8*)&Bs[row * 64 + p * 8];
      }
#pragma unroll
      for (int mt = 0; mt < 2; mt++) {
#pragma unroll
        for (int nt = 0; nt < 4; nt++) {
          acc[mt][nt] = __builtin_amdgcn_mfma_f32_16x16x32_bf16(a[mt], b[nt], acc[mt][nt], 0, 0, 0);
        }
      }
    }
    __syncthreads();
  }
  // fused epilogue: gates + blend + row-norm rescale
  float snh[2][4], shh[2][4];
#pragma unroll
  for (int mt = 0; mt < 2; mt++) {
#pragma unroll
    for (int i = 0; i < 4; i++) {
      int r = mt * 16 + q * 4 + i;
      size_t grow = (size_t)(r0 + r);
      float a_nh = 0.f, a_h = 0.f;
#pragma unroll
      for (int nt = 0; nt < 4; nt++) {
        int c = wave * 64 + nt * 16 + mrow;
        float hc = tanhf(acc[mt][nt][i] + b2[c]);
        float zd = bf2f(G[grow * N1 + 512 + c]) + bd[c];
        float zu = bf2f(G[grow * N1 + 768 + c]) + bu[c];
        float dec = 0.1f + 9.9f / (1.0f + expf(-zd)) + 1e-6f;
        float u = 1.0f / (1.0f + expf(-zu));
        float hv = h[grow * MEM + c];
        float nh = (1.0f - u) * (hv / dec) + u * hc;
        acc[mt][nt][i] = nh;  // reuse acc regs to hold new_h
        a_nh += nh * nh;
        a_h += hv * hv;
      }
      snh[mt][i] = a_nh;
      shh[mt][i] = a_h;
    }
  }
#pragma unroll
  for (int m = 1; m <= 8; m <<= 1) {
#pragma unroll
    for (int mt = 0; mt < 2; mt++) {
#pragma unroll
      for (int i = 0; i < 4; i++) {
        snh[mt][i] += __shfl_xor(snh[mt][i], m, 64);
        shh[mt][i] += __shfl_xor(shh[mt][i], m, 64);
      }
    }
  }
  if (mrow == 0) {
#pragma unroll
    for (int mt = 0; mt < 2; mt++) {
#pragma unroll
      for (int i = 0; i < 4; i++) {
        int r = mt * 16 + q * 4 + i;
        red_nh[r][wave] = snh[mt][i];
        red_h[r][wave] = shh[mt][i];
      }
    }
  }
  __syncthreads();
  if (t < 32) {
    float tn = red_nh[t][0] + red_nh[t][1] + red_nh[t][2] + red_nh[t][3];
    float th = red_h[t][0] + red_h[t][1] + red_h[t][2] + red_h[t][3];
    float hn = fmaxf(sqrtf(th), 1e-6f);
    float nn = fmaxf(sqrtf(tn), 1e-12f);
    scl[t] = hn / nn;
  }
  __syncthreads();
#pragma unroll
  for (int mt = 0; mt < 2; mt++) {
#pragma unroll
    for (int i = 0; i < 4; i++) {
      int r = mt * 16 + q * 4 + i;
      size_t grow = (size_t)(r0 + r);
      float sc = scl[r];
#pragma unroll
      for (int nt = 0; nt < 4; nt++) {
        int c = wave * 64 + nt * 16 + mrow;
        out[grow * MEM + c] = acc[mt][nt][i] * sc;
      }
    }
  }
}

extern "C" void kernel_launch(void* const* d_in, const int* in_sizes, int n_in,
                              void* d_out, int out_size, void* d_ws, size_t ws_size,
                              hipStream_t stream) {
  const float* x   = (const float*)d_in[0];
  const float* h   = (const float*)d_in[1];
  const float* W1  = (const float*)d_in[2];
  const float* b1  = (const float*)d_in[3];
  const float* g1  = (const float*)d_in[4];
  const float* be1 = (const float*)d_in[5];
  const float* W2  = (const float*)d_in[6];
  const float* b2  = (const float*)d_in[7];
  const float* Wd  = (const float*)d_in[8];
  const float* bd  = (const float*)d_in[9];
  const float* Wu  = (const float*)d_in[10];
  const float* bu  = (const float*)d_in[11];
  float* out = (float*)d_out;

  // workspace layout (25.95 MB total — unchanged from round 2):
  char* ws = (char*)d_ws;
  u16* WT  = (u16*)(ws);             // [1024][4352] bf16   8,912,896 B
  u16* W2T = (u16*)(ws + 8912896);   // [256][512] bf16       262,144 B
  u16* G   = (u16*)(ws + 9175040);   // [8192][1024] bf16  16,777,216 B

  dim3 tb(32, 8);
  transpose_cast<<<dim3(512 / 32, D_IN / 32), tb, 0, stream>>>(W1, WT, D_IN, 512);
  transpose_cast<<<dim3(256 / 32, D_IN / 32), tb, 0, stream>>>(Wd, WT + (size_t)512 * D_IN, D_IN, 256);
  transpose_cast<<<dim3(256 / 32, D_IN / 32), tb, 0, stream>>>(Wu, WT + (size_t)768 * D_IN, D_IN, 256);
  transpose_cast<<<dim3(256 / 32, 512 / 32),  tb, 0, stream>>>(W2, W2T, 512, 256);

  gemm1_kernel<<<512, 256, 0, stream>>>(x, h, WT, G);
  ln_gelu_kernel<<<B_ROWS, 256, 0, stream>>>(G, b1, g1, be1);
  gemm2_epi_kernel<<<B_ROWS / 32, 256, 0, stream>>>(G, W2T, h, b2, bd, bu, out);
}

// Round 4
// 413.701 us; speedup vs baseline: 1.1138x; 1.1138x over previous
//
#include <hip/hip_runtime.h>
#include <stdint.h>

typedef unsigned short u16;

#define B_ROWS 8192
#define IN_DIM 4096
#define MEM 256
#define D_IN 4352   // MEM + IN_DIM
#define N1 1024     // 512 | 256 | 256
#define K2 512
#define LN_EPS 1e-5f

typedef __attribute__((ext_vector_type(4))) float f32x4;
typedef __attribute__((ext_vector_type(4))) uint32_t u32x4;
typedef __attribute__((ext_vector_type(4))) unsigned short u16x4;
typedef __attribute__((ext_vector_type(8))) short bf16x8;  // 8 bf16 in 4 VGPRs

#define AS1(p) ((__attribute__((address_space(1))) void*)(p))
#define AS3(p) ((__attribute__((address_space(3))) void*)(p))

__device__ __forceinline__ float bf2f(u16 u) {
  union { uint32_t u; float f; } c; c.u = ((uint32_t)u) << 16; return c.f;
}
__device__ __forceinline__ u16 f2bf(float f) {  // round-to-nearest-even
  union { float f; uint32_t u; } c; c.f = f;
  uint32_t r = (c.u + 0x7fffu + ((c.u >> 16) & 1u)) >> 16;
  return (u16)r;
}
__device__ __forceinline__ uint32_t fbits(float f) {
  union { float f; uint32_t u; } c; c.f = f; return c.u;
}
// pack bf16(b)<<16 | bf16(a), truncation (cheap; error ok at 0.325 threshold)
__device__ __forceinline__ uint32_t pack_trunc(float a, float b) {
  return (fbits(b) & 0xFFFF0000u) | (fbits(a) >> 16);
}

// -------- fused weight transpose+cast: {W1,Wd,Wu}[K][*] fp32 -> WT[1024][4352] bf16 --------
// 64x64 tiles, 256 threads; f32x4 coalesced loads, u16x4 stores.
__global__ __launch_bounds__(256)
void transpose_cast_fused(const float* __restrict__ W1, const float* __restrict__ Wd,
                          const float* __restrict__ Wu, u16* __restrict__ WT) {
  __shared__ u16 tile[64][68];  // [n][k], stride 68 u16 = 8B-aligned rows, low-conflict
  int n0 = blockIdx.x * 64, k0 = blockIdx.y * 64;
  const float* src; int srcN, ns0;
  if (n0 < 512)      { src = W1; srcN = 512; ns0 = n0; }
  else if (n0 < 768) { src = Wd; srcN = 256; ns0 = n0 - 512; }
  else               { src = Wu; srcN = 256; ns0 = n0 - 768; }
  int t = threadIdx.x;
  int rr = t >> 4;        // 0..15
  int c4 = (t & 15) * 4;  // 0..60
#pragma unroll
  for (int i = 0; i < 4; i++) {
    int k = i * 16 + rr;
    f32x4 v = *(const f32x4*)&src[(size_t)(k0 + k) * srcN + ns0 + c4];
    tile[c4 + 0][k] = f2bf(v[0]);
    tile[c4 + 1][k] = f2bf(v[1]);
    tile[c4 + 2][k] = f2bf(v[2]);
    tile[c4 + 3][k] = f2bf(v[3]);
  }
  __syncthreads();
#pragma unroll
  for (int i = 0; i < 4; i++) {
    int n = i * 16 + rr;
    u16x4 w;
    w.x = tile[n][c4 + 0];
    w.y = tile[n][c4 + 1];
    w.z = tile[n][c4 + 2];
    w.w = tile[n][c4 + 3];
    *(u16x4*)&WT[(size_t)(n0 + n) * D_IN + k0 + c4] = w;
  }
}

// -------- small transpose+cast for W2: src[K][N] fp32 -> dst[N][K] bf16 --------
__global__ void transpose_cast(const float* __restrict__ src, u16* __restrict__ dst,
                               int K, int N) {
  __shared__ u16 tile[32][34];
  int n0 = blockIdx.x * 32, k0 = blockIdx.y * 32;
  int tx = threadIdx.x, ty = threadIdx.y;  // (32, 8)
#pragma unroll
  for (int i = 0; i < 4; i++)
    tile[ty + i * 8][tx] = f2bf(src[(size_t)(k0 + ty + i * 8) * N + n0 + tx]);
  __syncthreads();
#pragma unroll
  for (int i = 0; i < 4; i++)
    dst[(size_t)(n0 + ty + i * 8) * K + k0 + tx] = tile[tx][ty + i * 8];
}

// -------- GEMM1: [h|x](fp32) @ WT^T(bf16) -> G bf16 [8192][1024] --------
// 128x128 tile, BK=64, 256 threads = 4 waves (2x2), 16x16x32 bf16 MFMA.
// Swizzle: by = b&63 so consecutive blocks (round-robin XCDs) share bx slices and
// each XCD's 64 resident blocks form an 8x8 (by x bx) patch -> 8-way L2 sharing of A AND B.
__global__ __launch_bounds__(256, 2)
void gemm1_kernel(const float* __restrict__ x, const float* __restrict__ h,
                  const u16* __restrict__ WT, u16* __restrict__ G) {
  __shared__ __attribute__((aligned(16))) u16 As[128 * 64];
  __shared__ __attribute__((aligned(16))) u16 Bs[128 * 64];
  const int t = threadIdx.x;
  const int lane = t & 63, wave = t >> 6;
  const int bx = blockIdx.x >> 6;  // N tile (8)
  const int by = blockIdx.x & 63;  // M tile (64)
  const int row0 = by * 128, col0 = bx * 128;
  const int q = lane >> 4, mrow = lane & 15;
  const int wm = wave >> 1, wn = wave & 1;

  int ar[4], ac[4];  // staging: row, (xor-swizzled) chunk col
#pragma unroll
  for (int j = 0; j < 4; j++) {
    int idx = j * 256 + t;
    int r = idx >> 3;
    ar[j] = r;
    ac[j] = (idx & 7) ^ (r & 7);
  }

  f32x4 acc[4][4] = {};

  for (int k0 = 0; k0 < D_IN; k0 += 64) {
    // B tile: async DMA, bf16 weights
#pragma unroll
    for (int j = 0; j < 4; j++) {
      const u16* gp = WT + (size_t)(col0 + ar[j]) * D_IN + k0 + ac[j] * 8;
      __builtin_amdgcn_global_load_lds(AS1(gp), AS3(&Bs[(j * 256 + t) * 8]), 16, 0, 0);
    }
    // A tile: fp32 -> bf16 cast during staging
#pragma unroll
    for (int j = 0; j < 4; j++) {
      int k = k0 + ac[j] * 8;
      const float* gp = (k < MEM) ? (h + (size_t)(row0 + ar[j]) * MEM + k)
                                  : (x + (size_t)(row0 + ar[j]) * IN_DIM + (k - MEM));
      f32x4 v0 = *(const f32x4*)gp;
      f32x4 v1 = *(const f32x4*)(gp + 4);
      u32x4 w;
      w.x = pack_trunc(v0[0], v0[1]);
      w.y = pack_trunc(v0[2], v0[3]);
      w.z = pack_trunc(v1[0], v1[1]);
      w.w = pack_trunc(v1[2], v1[3]);
      *(u32x4*)&As[(j * 256 + t) * 8] = w;
    }
    __syncthreads();
#pragma unroll
    for (int kk = 0; kk < 2; kk++) {
      bf16x8 a[4], b[4];
#pragma unroll
      for (int mt = 0; mt < 4; mt++) {
        int row = wm * 64 + mt * 16 + mrow;
        int p = (kk * 4 + q) ^ (mrow & 7);
        a[mt] = *(const bf16x8*)&As[row * 64 + p * 8];
      }
#pragma unroll
      for (int nt = 0; nt < 4; nt++) {
        int row = wn * 64 + nt * 16 + mrow;
        int p = (kk * 4 + q) ^ (mrow & 7);
        b[nt] = *(const bf16x8*)&Bs[row * 64 + p * 8];
      }
#pragma unroll
      for (int mt = 0; mt < 4; mt++) {
#pragma unroll
        for (int nt = 0; nt < 4; nt++) {
          acc[mt][nt] = __builtin_amdgcn_mfma_f32_16x16x32_bf16(a[mt], b[nt], acc[mt][nt], 0, 0, 0);
        }
      }
    }
    __syncthreads();
  }
  // C/D layout: col=lane&15, row=(lane>>4)*4+reg  [m89-verified]
#pragma unroll
  for (int mt = 0; mt < 4; mt++) {
#pragma unroll
    for (int nt = 0; nt < 4; nt++) {
#pragma unroll
      for (int i = 0; i < 4; i++) {
        int row = row0 + wm * 64 + mt * 16 + q * 4 + i;
        int col = col0 + wn * 64 + nt * 16 + mrow;
        G[(size_t)row * N1 + col] = f2bf(acc[mt][nt][i]);
      }
    }
  }
}

// -------- LN + exact GELU, IN PLACE on G[:, :512], vectorized u32 access --------
__global__ __launch_bounds__(256)
void ln_gelu_kernel(u16* __restrict__ G, const float* __restrict__ b1,
                    const float* __restrict__ g1, const float* __restrict__ be1) {
  int r = blockIdx.x;
  int t = threadIdx.x;
  u16* row = G + (size_t)r * N1;
  uint32_t w = *(const uint32_t*)&row[2 * t];  // elems 2t, 2t+1
  float z0 = bf2f((u16)(w & 0xffff)) + b1[2 * t];
  float z1 = bf2f((u16)(w >> 16)) + b1[2 * t + 1];
  float s = z0 + z1, ss = z0 * z0 + z1 * z1;
#pragma unroll
  for (int m = 32; m >= 1; m >>= 1) {
    s += __shfl_xor(s, m, 64);
    ss += __shfl_xor(ss, m, 64);
  }
  __shared__ float rs[4], rss[4];
  int lane = t & 63, wave = t >> 6;
  if (lane == 0) { rs[wave] = s; rss[wave] = ss; }
  __syncthreads();
  float S = rs[0] + rs[1] + rs[2] + rs[3];
  float SS = rss[0] + rss[1] + rss[2] + rss[3];
  float mu = S * (1.0f / 512.0f);
  float var = SS * (1.0f / 512.0f) - mu * mu;
  float rstd = rsqrtf(var + LN_EPS);
  float y0 = (z0 - mu) * rstd * g1[2 * t] + be1[2 * t];
  float y1 = (z1 - mu) * rstd * g1[2 * t + 1] + be1[2 * t + 1];
  float o0 = 0.5f * y0 * (1.0f + erff(y0 * 0.7071067811865475f));
  float o1 = 0.5f * y1 * (1.0f + erff(y1 * 0.7071067811865475f));
  *(uint32_t*)&row[2 * t] = ((uint32_t)f2bf(o1) << 16) | f2bf(o0);
}

// -------- GEMM2 + full epilogue -> out fp32 [8192][256] --------
// 32x256 tile (full output width), BK=64, 4 waves side-by-side in N.
// A = G[:, 0:512] (post LN+GELU, bf16), gates from G[:, 512:1024].
__global__ __launch_bounds__(256, 2)
void gemm2_epi_kernel(const u16* __restrict__ G, const u16* __restrict__ W2T,
                      const float* __restrict__ h,
                      const float* __restrict__ b2, const float* __restrict__ bd,
                      const float* __restrict__ bu, float* __restrict__ out) {
  __shared__ __attribute__((aligned(16))) u16 As[32 * 64];
  __shared__ __attribute__((aligned(16))) u16 Bs[256 * 64];
  __shared__ float red_nh[32][4], red_h[32][4], scl[32];
  const int t = threadIdx.x, lane = t & 63, wave = t >> 6;
  const int q = lane >> 4, mrow = lane & 15;
  const int r0 = blockIdx.x * 32;

  const int arA = t >> 3;
  const int acA = (t & 7) ^ (arA & 7);
  int brB[8], bcB[8];
#pragma unroll
  for (int j = 0; j < 8; j++) {
    int idx = j * 256 + t;
    brB[j] = idx >> 3;
    bcB[j] = (idx & 7) ^ (brB[j] & 7);
  }
  f32x4 acc[2][4] = {};
  for (int k0 = 0; k0 < K2; k0 += 64) {
    __builtin_amdgcn_global_load_lds(AS1(G + (size_t)(r0 + arA) * N1 + k0 + acA * 8),
                                     AS3(&As[t * 8]), 16, 0, 0);
#pragma unroll
    for (int j = 0; j < 8; j++) {
      __builtin_amdgcn_global_load_lds(AS1(W2T + (size_t)brB[j] * K2 + k0 + bcB[j] * 8),
                                       AS3(&Bs[(j * 256 + t) * 8]), 16, 0, 0);
    }
    __syncthreads();
#pragma unroll
    for (int kk = 0; kk < 2; kk++) {
      bf16x8 a[2], b[4];
#pragma unroll
      for (int mt = 0; mt < 2; mt++) {
        int row = mt * 16 + mrow;
        int p = (kk * 4 + q) ^ (row & 7);
        a[mt] = *(const bf16x8*)&As[row * 64 + p * 8];
      }
#pragma unroll
      for (int nt = 0; nt < 4; nt++) {
        int row = wave * 64 + nt * 16 + mrow;
        int p = (kk * 4 + q) ^ (row & 7);
        b[nt] = *(const bf16x8*)&Bs[row * 64 + p * 8];
      }
#pragma unroll
      for (int mt = 0; mt < 2; mt++) {
#pragma unroll
        for (int nt = 0; nt < 4; nt++) {
          acc[mt][nt] = __builtin_amdgcn_mfma_f32_16x16x32_bf16(a[mt], b[nt], acc[mt][nt], 0, 0, 0);
        }
      }
    }
    __syncthreads();
  }
  // fused epilogue: gates + blend + row-norm rescale
  float snh[2][4], shh[2][4];
#pragma unroll
  for (int mt = 0; mt < 2; mt++) {
#pragma unroll
    for (int i = 0; i < 4; i++) {
      int r = mt * 16 + q * 4 + i;
      size_t grow = (size_t)(r0 + r);
      float a_nh = 0.f, a_h = 0.f;
#pragma unroll
      for (int nt = 0; nt < 4; nt++) {
        int c = wave * 64 + nt * 16 + mrow;
        float hc = tanhf(acc[mt][nt][i] + b2[c]);
        float zd = bf2f(G[grow * N1 + 512 + c]) + bd[c];
        float zu = bf2f(G[grow * N1 + 768 + c]) + bu[c];
        float dec = 0.1f + 9.9f / (1.0f + expf(-zd)) + 1e-6f;
        float u = 1.0f / (1.0f + expf(-zu));
        float hv = h[grow * MEM + c];
        float nh = (1.0f - u) * (hv / dec) + u * hc;
        acc[mt][nt][i] = nh;  // reuse acc regs to hold new_h
        a_nh += nh * nh;
        a_h += hv * hv;
      }
      snh[mt][i] = a_nh;
      shh[mt][i] = a_h;
    }
  }
#pragma unroll
  for (int m = 1; m <= 8; m <<= 1) {
#pragma unroll
    for (int mt = 0; mt < 2; mt++) {
#pragma unroll
      for (int i = 0; i < 4; i++) {
        snh[mt][i] += __shfl_xor(snh[mt][i], m, 64);
        shh[mt][i] += __shfl_xor(shh[mt][i], m, 64);
      }
    }
  }
  if (mrow == 0) {
#pragma unroll
    for (int mt = 0; mt < 2; mt++) {
#pragma unroll
      for (int i = 0; i < 4; i++) {
        int r = mt * 16 + q * 4 + i;
        red_nh[r][wave] = snh[mt][i];
        red_h[r][wave] = shh[mt][i];
      }
    }
  }
  __syncthreads();
  if (t < 32) {
    float tn = red_nh[t][0] + red_nh[t][1] + red_nh[t][2] + red_nh[t][3];
    float th = red_h[t][0] + red_h[t][1] + red_h[t][2] + red_h[t][3];
    float hn = fmaxf(sqrtf(th), 1e-6f);
    float nn = fmaxf(sqrtf(tn), 1e-12f);
    scl[t] = hn / nn;
  }
  __syncthreads();
#pragma unroll
  for (int mt = 0; mt < 2; mt++) {
#pragma unroll
    for (int i = 0; i < 4; i++) {
      int r = mt * 16 + q * 4 + i;
      size_t grow = (size_t)(r0 + r);
      float sc = scl[r];
#pragma unroll
      for (int nt = 0; nt < 4; nt++) {
        int c = wave * 64 + nt * 16 + mrow;
        out[grow * MEM + c] = acc[mt][nt][i] * sc;
      }
    }
  }
}

extern "C" void kernel_launch(void* const* d_in, const int* in_sizes, int n_in,
                              void* d_out, int out_size, void* d_ws, size_t ws_size,
                              hipStream_t stream) {
  const float* x   = (const float*)d_in[0];
  const float* h   = (const float*)d_in[1];
  const float* W1  = (const float*)d_in[2];
  const float* b1  = (const float*)d_in[3];
  const float* g1  = (const float*)d_in[4];
  const float* be1 = (const float*)d_in[5];
  const float* W2  = (const float*)d_in[6];
  const float* b2  = (const float*)d_in[7];
  const float* Wd  = (const float*)d_in[8];
  const float* bd  = (const float*)d_in[9];
  const float* Wu  = (const float*)d_in[10];
  const float* bu  = (const float*)d_in[11];
  float* out = (float*)d_out;

  // workspace layout (25.95 MB total):
  char* ws = (char*)d_ws;
  u16* WT  = (u16*)(ws);             // [1024][4352] bf16   8,912,896 B
  u16* W2T = (u16*)(ws + 8912896);   // [256][512] bf16       262,144 B
  u16* G   = (u16*)(ws + 9175040);   // [8192][1024] bf16  16,777,216 B

  transpose_cast_fused<<<dim3(N1 / 64, D_IN / 64), 256, 0, stream>>>(W1, Wd, Wu, WT);
  transpose_cast<<<dim3(256 / 32, 512 / 32), dim3(32, 8), 0, stream>>>(W2, W2T, 512, 256);

  gemm1_kernel<<<512, 256, 0, stream>>>(x, h, WT, G);
  ln_gelu_kernel<<<B_ROWS, 256, 0, stream>>>(G, b1, g1, be1);
  gemm2_epi_kernel<<<B_ROWS / 32, 256, 0, stream>>>(G, W2T, h, b2, bd, bu, out);
}

// Round 5
// 388.077 us; speedup vs baseline: 1.1874x; 1.0660x over previous
//
#include <hip/hip_runtime.h>
#include <stdint.h>

typedef unsigned short u16;

#define B_ROWS 8192
#define IN_DIM 4096
#define MEM 256
#define D_IN 4352   // MEM + IN_DIM
#define N1 1024     // 512 | 256 | 256
#define K2 512
#define LN_EPS 1e-5f

typedef __attribute__((ext_vector_type(4))) float f32x4;
typedef __attribute__((ext_vector_type(4))) uint32_t u32x4;
typedef __attribute__((ext_vector_type(4))) unsigned short u16x4;
typedef __attribute__((ext_vector_type(8))) short bf16x8;  // 8 bf16 in 4 VGPRs

#define AS1(p) ((__attribute__((address_space(1))) void*)(p))
#define AS3(p) ((__attribute__((address_space(3))) void*)(p))

__device__ __forceinline__ float bf2f(u16 u) {
  union { uint32_t u; float f; } c; c.u = ((uint32_t)u) << 16; return c.f;
}
__device__ __forceinline__ u16 f2bf(float f) {  // round-to-nearest-even
  union { float f; uint32_t u; } c; c.f = f;
  uint32_t r = (c.u + 0x7fffu + ((c.u >> 16) & 1u)) >> 16;
  return (u16)r;
}
__device__ __forceinline__ uint32_t fbits(float f) {
  union { float f; uint32_t u; } c; c.f = f; return c.u;
}
// pack bf16(b)<<16 | bf16(a), truncation (cheap; error ok at 0.325 threshold)
__device__ __forceinline__ uint32_t pack_trunc(float a, float b) {
  return (fbits(b) & 0xFFFF0000u) | (fbits(a) >> 16);
}

// -------- fused weight transpose+cast: {W1,Wd,Wu}[K][*] fp32 -> WT[1024][4352] bf16 --------
__global__ __launch_bounds__(256)
void transpose_cast_fused(const float* __restrict__ W1, const float* __restrict__ Wd,
                          const float* __restrict__ Wu, u16* __restrict__ WT) {
  __shared__ u16 tile[64][68];
  int n0 = blockIdx.x * 64, k0 = blockIdx.y * 64;
  const float* src; int srcN, ns0;
  if (n0 < 512)      { src = W1; srcN = 512; ns0 = n0; }
  else if (n0 < 768) { src = Wd; srcN = 256; ns0 = n0 - 512; }
  else               { src = Wu; srcN = 256; ns0 = n0 - 768; }
  int t = threadIdx.x;
  int rr = t >> 4;        // 0..15
  int c4 = (t & 15) * 4;  // 0..60
#pragma unroll
  for (int i = 0; i < 4; i++) {
    int k = i * 16 + rr;
    f32x4 v = *(const f32x4*)&src[(size_t)(k0 + k) * srcN + ns0 + c4];
    tile[c4 + 0][k] = f2bf(v[0]);
    tile[c4 + 1][k] = f2bf(v[1]);
    tile[c4 + 2][k] = f2bf(v[2]);
    tile[c4 + 3][k] = f2bf(v[3]);
  }
  __syncthreads();
#pragma unroll
  for (int i = 0; i < 4; i++) {
    int n = i * 16 + rr;
    u16x4 w;
    w.x = tile[n][c4 + 0];
    w.y = tile[n][c4 + 1];
    w.z = tile[n][c4 + 2];
    w.w = tile[n][c4 + 3];
    *(u16x4*)&WT[(size_t)(n0 + n) * D_IN + k0 + c4] = w;
  }
}

// -------- small transpose+cast for W2 --------
__global__ void transpose_cast(const float* __restrict__ src, u16* __restrict__ dst,
                               int K, int N) {
  __shared__ u16 tile[32][34];
  int n0 = blockIdx.x * 32, k0 = blockIdx.y * 32;
  int tx = threadIdx.x, ty = threadIdx.y;  // (32, 8)
#pragma unroll
  for (int i = 0; i < 4; i++)
    tile[ty + i * 8][tx] = f2bf(src[(size_t)(k0 + ty + i * 8) * N + n0 + tx]);
  __syncthreads();
#pragma unroll
  for (int i = 0; i < 4; i++)
    dst[(size_t)(n0 + ty + i * 8) * K + k0 + tx] = tile[tx][ty + i * 8];
}

// -------- GEMM1: [h|x](fp32) @ WT^T(bf16) -> Gpart bf16 [8192][1024] --------
// 128x128 tile, BK=64, split-K via grid: b = part*512 + bx*64 + by.
// Per XCD (b%8 round-robin): 8 by x 8 bx x nparts patch -> 8-way L2 share of A and B.
__global__ __launch_bounds__(256, 4)
void gemm1_kernel(const float* __restrict__ x, const float* __restrict__ h,
                  const u16* __restrict__ WT, u16* __restrict__ G0,
                  u16* __restrict__ G1, int klen) {
  __shared__ __attribute__((aligned(16))) u16 As[128 * 64];
  __shared__ __attribute__((aligned(16))) u16 Bs[128 * 64];
  const int t = threadIdx.x;
  const int lane = t & 63, wave = t >> 6;
  const int by = blockIdx.x & 63;         // M tile (64)
  const int bx = (blockIdx.x >> 6) & 7;   // N tile (8)
  const int part = blockIdx.x >> 9;       // K part (0 or 1)
  const int kbase = part * klen;
  u16* __restrict__ Gout = part ? G1 : G0;
  const int row0 = by * 128, col0 = bx * 128;
  const int q = lane >> 4, mrow = lane & 15;
  const int wm = wave >> 1, wn = wave & 1;

  int ar[4], ac[4];  // staging: row, (xor-swizzled) chunk col
#pragma unroll
  for (int j = 0; j < 4; j++) {
    int idx = j * 256 + t;
    int r = idx >> 3;
    ar[j] = r;
    ac[j] = (idx & 7) ^ (r & 7);
  }

  f32x4 acc[4][4] = {};

  for (int k0 = kbase; k0 < kbase + klen; k0 += 64) {
    // B tile: async DMA, bf16 weights
#pragma unroll
    for (int j = 0; j < 4; j++) {
      const u16* gp = WT + (size_t)(col0 + ar[j]) * D_IN + k0 + ac[j] * 8;
      __builtin_amdgcn_global_load_lds(AS1(gp), AS3(&Bs[(j * 256 + t) * 8]), 16, 0, 0);
    }
    // A tile: fp32 -> bf16 cast during staging
#pragma unroll
    for (int j = 0; j < 4; j++) {
      int k = k0 + ac[j] * 8;
      const float* gp = (k < MEM) ? (h + (size_t)(row0 + ar[j]) * MEM + k)
                                  : (x + (size_t)(row0 + ar[j]) * IN_DIM + (k - MEM));
      f32x4 v0 = *(const f32x4*)gp;
      f32x4 v1 = *(const f32x4*)(gp + 4);
      u32x4 w;
      w.x = pack_trunc(v0[0], v0[1]);
      w.y = pack_trunc(v0[2], v0[3]);
      w.z = pack_trunc(v1[0], v1[1]);
      w.w = pack_trunc(v1[2], v1[3]);
      *(u32x4*)&As[(j * 256 + t) * 8] = w;
    }
    __syncthreads();
#pragma unroll
    for (int kk = 0; kk < 2; kk++) {
      bf16x8 a[4], b[4];
#pragma unroll
      for (int mt = 0; mt < 4; mt++) {
        int row = wm * 64 + mt * 16 + mrow;
        int p = (kk * 4 + q) ^ (mrow & 7);
        a[mt] = *(const bf16x8*)&As[row * 64 + p * 8];
      }
#pragma unroll
      for (int nt = 0; nt < 4; nt++) {
        int row = wn * 64 + nt * 16 + mrow;
        int p = (kk * 4 + q) ^ (mrow & 7);
        b[nt] = *(const bf16x8*)&Bs[row * 64 + p * 8];
      }
#pragma unroll
      for (int mt = 0; mt < 4; mt++) {
#pragma unroll
        for (int nt = 0; nt < 4; nt++) {
          acc[mt][nt] = __builtin_amdgcn_mfma_f32_16x16x32_bf16(a[mt], b[nt], acc[mt][nt], 0, 0, 0);
        }
      }
    }
    __syncthreads();
  }
  // C/D layout: col=lane&15, row=(lane>>4)*4+reg  [m89-verified]
#pragma unroll
  for (int mt = 0; mt < 4; mt++) {
#pragma unroll
    for (int nt = 0; nt < 4; nt++) {
#pragma unroll
      for (int i = 0; i < 4; i++) {
        int row = row0 + wm * 64 + mt * 16 + q * 4 + i;
        int col = col0 + wn * 64 + nt * 16 + mrow;
        Gout[(size_t)row * N1 + col] = f2bf(acc[mt][nt][i]);
      }
    }
  }
}

// -------- LN + exact GELU: z = G0+G1 (cols 0..511), result IN PLACE into G0 --------
__global__ __launch_bounds__(256)
void ln_gelu_kernel(u16* __restrict__ G0, const u16* __restrict__ G1,
                    const float* __restrict__ b1, const float* __restrict__ g1,
                    const float* __restrict__ be1, int nparts) {
  int r = blockIdx.x;
  int t = threadIdx.x;
  u16* row = G0 + (size_t)r * N1;
  uint32_t w = *(const uint32_t*)&row[2 * t];  // elems 2t, 2t+1
  float z0 = bf2f((u16)(w & 0xffff));
  float z1 = bf2f((u16)(w >> 16));
  if (nparts == 2) {
    uint32_t w1 = *(const uint32_t*)&G1[(size_t)r * N1 + 2 * t];
    z0 += bf2f((u16)(w1 & 0xffff));
    z1 += bf2f((u16)(w1 >> 16));
  }
  z0 += b1[2 * t];
  z1 += b1[2 * t + 1];
  float s = z0 + z1, ss = z0 * z0 + z1 * z1;
#pragma unroll
  for (int m = 32; m >= 1; m >>= 1) {
    s += __shfl_xor(s, m, 64);
    ss += __shfl_xor(ss, m, 64);
  }
  __shared__ float rs[4], rss[4];
  int lane = t & 63, wave = t >> 6;
  if (lane == 0) { rs[wave] = s; rss[wave] = ss; }
  __syncthreads();
  float S = rs[0] + rs[1] + rs[2] + rs[3];
  float SS = rss[0] + rss[1] + rss[2] + rss[3];
  float mu = S * (1.0f / 512.0f);
  float var = SS * (1.0f / 512.0f) - mu * mu;
  float rstd = rsqrtf(var + LN_EPS);
  float y0 = (z0 - mu) * rstd * g1[2 * t] + be1[2 * t];
  float y1 = (z1 - mu) * rstd * g1[2 * t + 1] + be1[2 * t + 1];
  float o0 = 0.5f * y0 * (1.0f + erff(y0 * 0.7071067811865475f));
  float o1 = 0.5f * y1 * (1.0f + erff(y1 * 0.7071067811865475f));
  *(uint32_t*)&row[2 * t] = ((uint32_t)f2bf(o1) << 16) | f2bf(o0);
}

// -------- GEMM2 + full epilogue -> out fp32 [8192][256] --------
// A = G0[:, 0:512] (post LN+GELU, bf16), gates from G0(+G1)[:, 512:1024].
__global__ __launch_bounds__(256, 2)
void gemm2_epi_kernel(const u16* __restrict__ G0, const u16* __restrict__ G1,
                      const u16* __restrict__ W2T, const float* __restrict__ h,
                      const float* __restrict__ b2, const float* __restrict__ bd,
                      const float* __restrict__ bu, float* __restrict__ out,
                      int nparts) {
  __shared__ __attribute__((aligned(16))) u16 As[32 * 64];
  __shared__ __attribute__((aligned(16))) u16 Bs[256 * 64];
  __shared__ float red_nh[32][4], red_h[32][4], scl[32];
  const int t = threadIdx.x, lane = t & 63, wave = t >> 6;
  const int q = lane >> 4, mrow = lane & 15;
  const int r0 = blockIdx.x * 32;

  const int arA = t >> 3;
  const int acA = (t & 7) ^ (arA & 7);
  int brB[8], bcB[8];
#pragma unroll
  for (int j = 0; j < 8; j++) {
    int idx = j * 256 + t;
    brB[j] = idx >> 3;
    bcB[j] = (idx & 7) ^ (brB[j] & 7);
  }
  f32x4 acc[2][4] = {};
  for (int k0 = 0; k0 < K2; k0 += 64) {
    __builtin_amdgcn_global_load_lds(AS1(G0 + (size_t)(r0 + arA) * N1 + k0 + acA * 8),
                                     AS3(&As[t * 8]), 16, 0, 0);
#pragma unroll
    for (int j = 0; j < 8; j++) {
      __builtin_amdgcn_global_load_lds(AS1(W2T + (size_t)brB[j] * K2 + k0 + bcB[j] * 8),
                                       AS3(&Bs[(j * 256 + t) * 8]), 16, 0, 0);
    }
    __syncthreads();
#pragma unroll
    for (int kk = 0; kk < 2; kk++) {
      bf16x8 a[2], b[4];
#pragma unroll
      for (int mt = 0; mt < 2; mt++) {
        int row = mt * 16 + mrow;
        int p = (kk * 4 + q) ^ (row & 7);
        a[mt] = *(const bf16x8*)&As[row * 64 + p * 8];
      }
#pragma unroll
      for (int nt = 0; nt < 4; nt++) {
        int row = wave * 64 + nt * 16 + mrow;
        int p = (kk * 4 + q) ^ (row & 7);
        b[nt] = *(const bf16x8*)&Bs[row * 64 + p * 8];
      }
#pragma unroll
      for (int mt = 0; mt < 2; mt++) {
#pragma unroll
        for (int nt = 0; nt < 4; nt++) {
          acc[mt][nt] = __builtin_amdgcn_mfma_f32_16x16x32_bf16(a[mt], b[nt], acc[mt][nt], 0, 0, 0);
        }
      }
    }
    __syncthreads();
  }
  // fused epilogue: gates + blend + row-norm rescale
  float snh[2][4], shh[2][4];
#pragma unroll
  for (int mt = 0; mt < 2; mt++) {
#pragma unroll
    for (int i = 0; i < 4; i++) {
      int r = mt * 16 + q * 4 + i;
      size_t grow = (size_t)(r0 + r);
      float a_nh = 0.f, a_h = 0.f;
#pragma unroll
      for (int nt = 0; nt < 4; nt++) {
        int c = wave * 64 + nt * 16 + mrow;
        float hc = tanhf(acc[mt][nt][i] + b2[c]);
        float zd = bf2f(G0[grow * N1 + 512 + c]);
        float zu = bf2f(G0[grow * N1 + 768 + c]);
        if (nparts == 2) {
          zd += bf2f(G1[grow * N1 + 512 + c]);
          zu += bf2f(G1[grow * N1 + 768 + c]);
        }
        zd += bd[c];
        zu += bu[c];
        float dec = 0.1f + 9.9f / (1.0f + expf(-zd)) + 1e-6f;
        float u = 1.0f / (1.0f + expf(-zu));
        float hv = h[grow * MEM + c];
        float nh = (1.0f - u) * (hv / dec) + u * hc;
        acc[mt][nt][i] = nh;  // reuse acc regs to hold new_h
        a_nh += nh * nh;
        a_h += hv * hv;
      }
      snh[mt][i] = a_nh;
      shh[mt][i] = a_h;
    }
  }
#pragma unroll
  for (int m = 1; m <= 8; m <<= 1) {
#pragma unroll
    for (int mt = 0; mt < 2; mt++) {
#pragma unroll
      for (int i = 0; i < 4; i++) {
        snh[mt][i] += __shfl_xor(snh[mt][i], m, 64);
        shh[mt][i] += __shfl_xor(shh[mt][i], m, 64);
      }
    }
  }
  if (mrow == 0) {
#pragma unroll
    for (int mt = 0; mt < 2; mt++) {
#pragma unroll
      for (int i = 0; i < 4; i++) {
        int r = mt * 16 + q * 4 + i;
        red_nh[r][wave] = snh[mt][i];
        red_h[r][wave] = shh[mt][i];
      }
    }
  }
  __syncthreads();
  if (t < 32) {
    float tn = red_nh[t][0] + red_nh[t][1] + red_nh[t][2] + red_nh[t][3];
    float th = red_h[t][0] + red_h[t][1] + red_h[t][2] + red_h[t][3];
    float hn = fmaxf(sqrtf(th), 1e-6f);
    float nn = fmaxf(sqrtf(tn), 1e-12f);
    scl[t] = hn / nn;
  }
  __syncthreads();
#pragma unroll
  for (int mt = 0; mt < 2; mt++) {
#pragma unroll
    for (int i = 0; i < 4; i++) {
      int r = mt * 16 + q * 4 + i;
      size_t grow = (size_t)(r0 + r);
      float sc = scl[r];
#pragma unroll
      for (int nt = 0; nt < 4; nt++) {
        int c = wave * 64 + nt * 16 + mrow;
        out[grow * MEM + c] = acc[mt][nt][i] * sc;
      }
    }
  }
}

extern "C" void kernel_launch(void* const* d_in, const int* in_sizes, int n_in,
                              void* d_out, int out_size, void* d_ws, size_t ws_size,
                              hipStream_t stream) {
  const float* x   = (const float*)d_in[0];
  const float* h   = (const float*)d_in[1];
  const float* W1  = (const float*)d_in[2];
  const float* b1  = (const float*)d_in[3];
  const float* g1  = (const float*)d_in[4];
  const float* be1 = (const float*)d_in[5];
  const float* W2  = (const float*)d_in[6];
  const float* b2  = (const float*)d_in[7];
  const float* Wd  = (const float*)d_in[8];
  const float* bd  = (const float*)d_in[9];
  const float* Wu  = (const float*)d_in[10];
  const float* bu  = (const float*)d_in[11];
  float* out = (float*)d_out;

  // workspace layout: WT 8,912,896 | W2T 262,144 | G0 16,777,216 | [G1 16,777,216]
  char* ws = (char*)d_ws;
  u16* WT  = (u16*)(ws);
  u16* W2T = (u16*)(ws + 8912896);
  u16* G0  = (u16*)(ws + 9175040);
  u16* G1  = (u16*)(ws + 25952256);

  // split-K=2 needs 42,729,472 B of workspace; fall back to single-K (25,952,256 B proven)
  const int nparts = (ws_size >= 42729472u) ? 2 : 1;
  const int klen = D_IN / nparts;

  transpose_cast_fused<<<dim3(N1 / 64, D_IN / 64), 256, 0, stream>>>(W1, Wd, Wu, WT);
  transpose_cast<<<dim3(256 / 32, 512 / 32), dim3(32, 8), 0, stream>>>(W2, W2T, 512, 256);

  gemm1_kernel<<<512 * nparts, 256, 0, stream>>>(x, h, WT, G0, G1, klen);
  ln_gelu_kernel<<<B_ROWS, 256, 0, stream>>>(G0, G1, b1, g1, be1, nparts);
  gemm2_epi_kernel<<<B_ROWS / 32, 256, 0, stream>>>(G0, G1, W2T, h, b2, bd, bu, out, nparts);
}

// Round 6
// 343.159 us; speedup vs baseline: 1.3428x; 1.1309x over previous
//
#include <hip/hip_runtime.h>
#include <stdint.h>

typedef unsigned short u16;

#define B_ROWS 8192
#define IN_DIM 4096
#define MEM 256
#define D_IN 4352   // MEM + IN_DIM
#define N1 1024     // 512 | 256 | 256
#define K2 512
#define LN_EPS 1e-5f

typedef __attribute__((ext_vector_type(4))) float f32x4;
typedef __attribute__((ext_vector_type(4))) uint32_t u32x4;
typedef __attribute__((ext_vector_type(4))) unsigned short u16x4;
typedef __attribute__((ext_vector_type(8))) short bf16x8;  // 8 bf16 in 4 VGPRs

#define AS1(p) ((__attribute__((address_space(1))) void*)(p))
#define AS3(p) ((__attribute__((address_space(3))) void*)(p))

__device__ __forceinline__ float bf2f(u16 u) {
  union { uint32_t u; float f; } c; c.u = ((uint32_t)u) << 16; return c.f;
}
__device__ __forceinline__ u16 f2bf(float f) {  // round-to-nearest-even
  union { float f; uint32_t u; } c; c.f = f;
  uint32_t r = (c.u + 0x7fffu + ((c.u >> 16) & 1u)) >> 16;
  return (u16)r;
}
__device__ __forceinline__ uint32_t fbits(float f) {
  union { float f; uint32_t u; } c; c.f = f; return c.u;
}
__device__ __forceinline__ uint32_t pack_rne(float a, float b) {
  return ((uint32_t)f2bf(b) << 16) | f2bf(a);
}
// truncation pack (used only in fallback inline-cast gemm1)
__device__ __forceinline__ uint32_t pack_trunc(float a, float b) {
  return (fbits(b) & 0xFFFF0000u) | (fbits(a) >> 16);
}

// -------- cast [h|x] fp32 -> Abf bf16 [8192][4352] --------
// blocks [0,1024): h (8192x256); blocks [1024,17408): x (8192x4096). 8 elems/thread.
__global__ __launch_bounds__(256)
void cast_A_kernel(const float* __restrict__ h, const float* __restrict__ x,
                   u16* __restrict__ Abf) {
  int b = blockIdx.x, t = threadIdx.x;
  const float* src; int r, c, dcol;
  if (b < 1024) {
    int g = (b * 256 + t) * 8;
    src = h + g; r = g >> 8; c = g & 255; dcol = c;
  } else {
    int g = ((b - 1024) * 256 + t) * 8;
    src = x + g; r = g >> 12; c = g & 4095; dcol = MEM + c;
  }
  f32x4 v0 = *(const f32x4*)src;
  f32x4 v1 = *(const f32x4*)(src + 4);
  u32x4 w;
  w.x = pack_rne(v0[0], v0[1]);
  w.y = pack_rne(v0[2], v0[3]);
  w.z = pack_rne(v1[0], v1[1]);
  w.w = pack_rne(v1[2], v1[3]);
  *(u32x4*)&Abf[(size_t)r * D_IN + dcol] = w;
}

// -------- fused weight transpose+cast: {W1,Wd,Wu}[K][*] fp32 -> WT[1024][4352] bf16 --------
__global__ __launch_bounds__(256)
void transpose_cast_fused(const float* __restrict__ W1, const float* __restrict__ Wd,
                          const float* __restrict__ Wu, u16* __restrict__ WT) {
  __shared__ u16 tile[64][68];
  int n0 = blockIdx.x * 64, k0 = blockIdx.y * 64;
  const float* src; int srcN, ns0;
  if (n0 < 512)      { src = W1; srcN = 512; ns0 = n0; }
  else if (n0 < 768) { src = Wd; srcN = 256; ns0 = n0 - 512; }
  else               { src = Wu; srcN = 256; ns0 = n0 - 768; }
  int t = threadIdx.x;
  int rr = t >> 4;        // 0..15
  int c4 = (t & 15) * 4;  // 0..60
#pragma unroll
  for (int i = 0; i < 4; i++) {
    int k = i * 16 + rr;
    f32x4 v = *(const f32x4*)&src[(size_t)(k0 + k) * srcN + ns0 + c4];
    tile[c4 + 0][k] = f2bf(v[0]);
    tile[c4 + 1][k] = f2bf(v[1]);
    tile[c4 + 2][k] = f2bf(v[2]);
    tile[c4 + 3][k] = f2bf(v[3]);
  }
  __syncthreads();
#pragma unroll
  for (int i = 0; i < 4; i++) {
    int n = i * 16 + rr;
    u16x4 w;
    w.x = tile[n][c4 + 0];
    w.y = tile[n][c4 + 1];
    w.z = tile[n][c4 + 2];
    w.w = tile[n][c4 + 3];
    *(u16x4*)&WT[(size_t)(n0 + n) * D_IN + k0 + c4] = w;
  }
}

// -------- small transpose+cast for W2 --------
__global__ void transpose_cast(const float* __restrict__ src, u16* __restrict__ dst,
                               int K, int N) {
  __shared__ u16 tile[32][34];
  int n0 = blockIdx.x * 32, k0 = blockIdx.y * 32;
  int tx = threadIdx.x, ty = threadIdx.y;  // (32, 8)
#pragma unroll
  for (int i = 0; i < 4; i++)
    tile[ty + i * 8][tx] = f2bf(src[(size_t)(k0 + ty + i * 8) * N + n0 + tx]);
  __syncthreads();
#pragma unroll
  for (int i = 0; i < 4; i++)
    dst[(size_t)(n0 + ty + i * 8) * K + k0 + tx] = tile[tx][ty + i * 8];
}

// -------- GEMM1 (pre-cast A): Abf(bf16) @ WT^T(bf16) -> Gpart bf16 --------
// m97 structure: both operands via global_load_lds width=16. 128x128, BK=64, split-K.
__global__ __launch_bounds__(256, 4)
void gemm1_pre_kernel(const u16* __restrict__ Abf, const u16* __restrict__ WT,
                      u16* __restrict__ G0, u16* __restrict__ G1, int klen) {
  __shared__ __attribute__((aligned(16))) u16 As[128 * 64];
  __shared__ __attribute__((aligned(16))) u16 Bs[128 * 64];
  const int t = threadIdx.x;
  const int lane = t & 63, wave = t >> 6;
  const int by = blockIdx.x & 63;         // M tile (64)
  const int bx = (blockIdx.x >> 6) & 7;   // N tile (8)
  const int part = blockIdx.x >> 9;       // K part
  const int kbase = part * klen;
  u16* __restrict__ Gout = part ? G1 : G0;
  const int row0 = by * 128, col0 = bx * 128;
  const int q = lane >> 4, mrow = lane & 15;
  const int wm = wave >> 1, wn = wave & 1;

  int ar[4], ac[4];
#pragma unroll
  for (int j = 0; j < 4; j++) {
    int idx = j * 256 + t;
    int r = idx >> 3;
    ar[j] = r;
    ac[j] = (idx & 7) ^ (r & 7);
  }

  f32x4 acc[4][4] = {};

  for (int k0 = kbase; k0 < kbase + klen; k0 += 64) {
#pragma unroll
    for (int j = 0; j < 4; j++) {
      const u16* gp = WT + (size_t)(col0 + ar[j]) * D_IN + k0 + ac[j] * 8;
      __builtin_amdgcn_global_load_lds(AS1(gp), AS3(&Bs[(j * 256 + t) * 8]), 16, 0, 0);
    }
#pragma unroll
    for (int j = 0; j < 4; j++) {
      const u16* gp = Abf + (size_t)(row0 + ar[j]) * D_IN + k0 + ac[j] * 8;
      __builtin_amdgcn_global_load_lds(AS1(gp), AS3(&As[(j * 256 + t) * 8]), 16, 0, 0);
    }
    __syncthreads();
#pragma unroll
    for (int kk = 0; kk < 2; kk++) {
      bf16x8 a[4], b[4];
#pragma unroll
      for (int mt = 0; mt < 4; mt++) {
        int row = wm * 64 + mt * 16 + mrow;
        int p = (kk * 4 + q) ^ (mrow & 7);
        a[mt] = *(const bf16x8*)&As[row * 64 + p * 8];
      }
#pragma unroll
      for (int nt = 0; nt < 4; nt++) {
        int row = wn * 64 + nt * 16 + mrow;
        int p = (kk * 4 + q) ^ (mrow & 7);
        b[nt] = *(const bf16x8*)&Bs[row * 64 + p * 8];
      }
#pragma unroll
      for (int mt = 0; mt < 4; mt++) {
#pragma unroll
        for (int nt = 0; nt < 4; nt++) {
          acc[mt][nt] = __builtin_amdgcn_mfma_f32_16x16x32_bf16(a[mt], b[nt], acc[mt][nt], 0, 0, 0);
        }
      }
    }
    __syncthreads();
  }
#pragma unroll
  for (int mt = 0; mt < 4; mt++) {
#pragma unroll
    for (int nt = 0; nt < 4; nt++) {
#pragma unroll
      for (int i = 0; i < 4; i++) {
        int row = row0 + wm * 64 + mt * 16 + q * 4 + i;
        int col = col0 + wn * 64 + nt * 16 + mrow;
        Gout[(size_t)row * N1 + col] = f2bf(acc[mt][nt][i]);
      }
    }
  }
}

// -------- fallback GEMM1 (inline fp32->bf16 A staging), round-5 proven --------
__global__ __launch_bounds__(256, 4)
void gemm1_inline_kernel(const float* __restrict__ x, const float* __restrict__ h,
                         const u16* __restrict__ WT, u16* __restrict__ G0,
                         u16* __restrict__ G1, int klen) {
  __shared__ __attribute__((aligned(16))) u16 As[128 * 64];
  __shared__ __attribute__((aligned(16))) u16 Bs[128 * 64];
  const int t = threadIdx.x;
  const int lane = t & 63, wave = t >> 6;
  const int by = blockIdx.x & 63;
  const int bx = (blockIdx.x >> 6) & 7;
  const int part = blockIdx.x >> 9;
  const int kbase = part * klen;
  u16* __restrict__ Gout = part ? G1 : G0;
  const int row0 = by * 128, col0 = bx * 128;
  const int q = lane >> 4, mrow = lane & 15;
  const int wm = wave >> 1, wn = wave & 1;

  int ar[4], ac[4];
#pragma unroll
  for (int j = 0; j < 4; j++) {
    int idx = j * 256 + t;
    int r = idx >> 3;
    ar[j] = r;
    ac[j] = (idx & 7) ^ (r & 7);
  }
  f32x4 acc[4][4] = {};
  for (int k0 = kbase; k0 < kbase + klen; k0 += 64) {
#pragma unroll
    for (int j = 0; j < 4; j++) {
      const u16* gp = WT + (size_t)(col0 + ar[j]) * D_IN + k0 + ac[j] * 8;
      __builtin_amdgcn_global_load_lds(AS1(gp), AS3(&Bs[(j * 256 + t) * 8]), 16, 0, 0);
    }
#pragma unroll
    for (int j = 0; j < 4; j++) {
      int k = k0 + ac[j] * 8;
      const float* gp = (k < MEM) ? (h + (size_t)(row0 + ar[j]) * MEM + k)
                                  : (x + (size_t)(row0 + ar[j]) * IN_DIM + (k - MEM));
      f32x4 v0 = *(const f32x4*)gp;
      f32x4 v1 = *(const f32x4*)(gp + 4);
      u32x4 w;
      w.x = pack_trunc(v0[0], v0[1]);
      w.y = pack_trunc(v0[2], v0[3]);
      w.z = pack_trunc(v1[0], v1[1]);
      w.w = pack_trunc(v1[2], v1[3]);
      *(u32x4*)&As[(j * 256 + t) * 8] = w;
    }
    __syncthreads();
#pragma unroll
    for (int kk = 0; kk < 2; kk++) {
      bf16x8 a[4], b[4];
#pragma unroll
      for (int mt = 0; mt < 4; mt++) {
        int row = wm * 64 + mt * 16 + mrow;
        int p = (kk * 4 + q) ^ (mrow & 7);
        a[mt] = *(const bf16x8*)&As[row * 64 + p * 8];
      }
#pragma unroll
      for (int nt = 0; nt < 4; nt++) {
        int row = wn * 64 + nt * 16 + mrow;
        int p = (kk * 4 + q) ^ (mrow & 7);
        b[nt] = *(const bf16x8*)&Bs[row * 64 + p * 8];
      }
#pragma unroll
      for (int mt = 0; mt < 4; mt++) {
#pragma unroll
        for (int nt = 0; nt < 4; nt++) {
          acc[mt][nt] = __builtin_amdgcn_mfma_f32_16x16x32_bf16(a[mt], b[nt], acc[mt][nt], 0, 0, 0);
        }
      }
    }
    __syncthreads();
  }
#pragma unroll
  for (int mt = 0; mt < 4; mt++) {
#pragma unroll
    for (int nt = 0; nt < 4; nt++) {
#pragma unroll
      for (int i = 0; i < 4; i++) {
        int row = row0 + wm * 64 + mt * 16 + q * 4 + i;
        int col = col0 + wn * 64 + nt * 16 + mrow;
        Gout[(size_t)row * N1 + col] = f2bf(acc[mt][nt][i]);
      }
    }
  }
}

// -------- fused LN+GELU+GEMM2+epilogue -> out fp32 [8192][256] --------
// 16-row tiles, grid 512. Phase 1: LN+GELU of G[r0:r0+16, 0:512] into LDS As (bf16).
// Phase 2: K-loop MFMA vs W2T. Phase 3: gates+blend+row-norm rescale.
__global__ __launch_bounds__(256, 2)
void fused_ln_gemm2_kernel(const u16* __restrict__ G0, const u16* __restrict__ G1,
                           const u16* __restrict__ W2T, const float* __restrict__ h,
                           const float* __restrict__ b1v, const float* __restrict__ g1v,
                           const float* __restrict__ be1v, const float* __restrict__ b2,
                           const float* __restrict__ bd, const float* __restrict__ bu,
                           float* __restrict__ out, int nparts) {
  __shared__ __attribute__((aligned(16))) u16 As[16 * 512];   // 16 KB, full A tile
  __shared__ __attribute__((aligned(16))) u16 Bs[256 * 64];   // 32 KB per K-chunk
  __shared__ float redA[16][4], redB[16][4], scl[16];
  const int t = threadIdx.x, lane = t & 63, wave = t >> 6;
  const int q = lane >> 4, mrow = lane & 15;
  const int r0 = blockIdx.x * 16;

  // ---- Phase 1: LN + exact GELU ----
  {
    const int lr = t & 15;   // row in tile
    const int lc = t >> 4;   // 32-col chunk [0,16)
    float z[32];
    const u16* g0p = G0 + (size_t)(r0 + lr) * N1 + lc * 32;
    const u16* g1p = G1 + (size_t)(r0 + lr) * N1 + lc * 32;
    float s = 0.f, ss = 0.f;
#pragma unroll
    for (int j = 0; j < 4; j++) {
      u32x4 w0 = *(const u32x4*)(g0p + j * 8);
      u32x4 w1;
      if (nparts == 2) w1 = *(const u32x4*)(g1p + j * 8);
#pragma unroll
      for (int e = 0; e < 4; e++) {
        float lo = bf2f((u16)(w0[e] & 0xffff));
        float hi = bf2f((u16)(w0[e] >> 16));
        if (nparts == 2) {
          lo += bf2f((u16)(w1[e] & 0xffff));
          hi += bf2f((u16)(w1[e] >> 16));
        }
        int cb = lc * 32 + j * 8 + e * 2;
        lo += b1v[cb];
        hi += b1v[cb + 1];
        z[j * 8 + e * 2] = lo;
        z[j * 8 + e * 2 + 1] = hi;
        s += lo + hi;
        ss += lo * lo + hi * hi;
      }
    }
    s += __shfl_xor(s, 16, 64);  s += __shfl_xor(s, 32, 64);
    ss += __shfl_xor(ss, 16, 64); ss += __shfl_xor(ss, 32, 64);
    if (lane < 16) { redA[lr][wave] = s; redB[lr][wave] = ss; }
    __syncthreads();
    float S  = redA[lr][0] + redA[lr][1] + redA[lr][2] + redA[lr][3];
    float SS = redB[lr][0] + redB[lr][1] + redB[lr][2] + redB[lr][3];
    float mu = S * (1.0f / 512.0f);
    float var = SS * (1.0f / 512.0f) - mu * mu;
    float rstd = rsqrtf(var + LN_EPS);
#pragma unroll
    for (int j = 0; j < 4; j++) {
      u32x4 wpk;
#pragma unroll
      for (int e = 0; e < 4; e++) {
        int cb = lc * 32 + j * 8 + e * 2;
        float y0 = (z[j * 8 + e * 2] - mu) * rstd * g1v[cb] + be1v[cb];
        float y1 = (z[j * 8 + e * 2 + 1] - mu) * rstd * g1v[cb + 1] + be1v[cb + 1];
        float o0 = 0.5f * y0 * (1.0f + erff(y0 * 0.7071067811865475f));
        float o1 = 0.5f * y1 * (1.0f + erff(y1 * 0.7071067811865475f));
        wpk[e] = pack_rne(o0, o1);
      }
      int p = lc * 4 + j;
      int ps = p ^ (lr & 7);
      *(u32x4*)&As[lr * 512 + ps * 8] = wpk;
    }
  }
  // As writes are covered by the first K-loop __syncthreads()

  // ---- Phase 2: GEMM vs W2T ----
  int brB[8], bcB[8];
#pragma unroll
  for (int j = 0; j < 8; j++) {
    int idx = j * 256 + t;
    brB[j] = idx >> 3;
    bcB[j] = (idx & 7) ^ (brB[j] & 7);
  }
  f32x4 acc[4] = {};
  for (int k0 = 0; k0 < K2; k0 += 64) {
#pragma unroll
    for (int j = 0; j < 8; j++) {
      __builtin_amdgcn_global_load_lds(AS1(W2T + (size_t)brB[j] * K2 + k0 + bcB[j] * 8),
                                       AS3(&Bs[(j * 256 + t) * 8]), 16, 0, 0);
    }
    __syncthreads();
#pragma unroll
    for (int kk = 0; kk < 2; kk++) {
      int kw = (k0 >> 5) + kk;  // 32-wide K window [0,16)
      int pa = (kw * 4 + q) ^ (mrow & 7);
      bf16x8 a = *(const bf16x8*)&As[mrow * 512 + pa * 8];
      bf16x8 b[4];
#pragma unroll
      for (int nt = 0; nt < 4; nt++) {
        int row = wave * 64 + nt * 16 + mrow;
        int p = (kk * 4 + q) ^ (row & 7);
        b[nt] = *(const bf16x8*)&Bs[row * 64 + p * 8];
      }
#pragma unroll
      for (int nt = 0; nt < 4; nt++) {
        acc[nt] = __builtin_amdgcn_mfma_f32_16x16x32_bf16(a, b[nt], acc[nt], 0, 0, 0);
      }
    }
    __syncthreads();
  }

  // ---- Phase 3: gates + blend + row-norm rescale ----
  float snh[4], shh[4];
#pragma unroll
  for (int i = 0; i < 4; i++) {
    int r = q * 4 + i;
    size_t grow = (size_t)(r0 + r);
    float a_nh = 0.f, a_h = 0.f;
#pragma unroll
    for (int nt = 0; nt < 4; nt++) {
      int c = wave * 64 + nt * 16 + mrow;
      float hc = tanhf(acc[nt][i] + b2[c]);
      float zd = bf2f(G0[grow * N1 + 512 + c]);
      float zu = bf2f(G0[grow * N1 + 768 + c]);
      if (nparts == 2) {
        zd += bf2f(G1[grow * N1 + 512 + c]);
        zu += bf2f(G1[grow * N1 + 768 + c]);
      }
      zd += bd[c];
      zu += bu[c];
      float dec = 0.1f + 9.9f / (1.0f + expf(-zd)) + 1e-6f;
      float u = 1.0f / (1.0f + expf(-zu));
      float hv = h[grow * MEM + c];
      float nh = (1.0f - u) * (hv / dec) + u * hc;
      acc[nt][i] = nh;
      a_nh += nh * nh;
      a_h += hv * hv;
    }
    snh[i] = a_nh;
    shh[i] = a_h;
  }
#pragma unroll
  for (int m = 1; m <= 8; m <<= 1) {
#pragma unroll
    for (int i = 0; i < 4; i++) {
      snh[i] += __shfl_xor(snh[i], m, 64);
      shh[i] += __shfl_xor(shh[i], m, 64);
    }
  }
  if (mrow == 0) {
#pragma unroll
    for (int i = 0; i < 4; i++) {
      int r = q * 4 + i;
      redA[r][wave] = snh[i];
      redB[r][wave] = shh[i];
    }
  }
  __syncthreads();
  if (t < 16) {
    float tn = redA[t][0] + redA[t][1] + redA[t][2] + redA[t][3];
    float th = redB[t][0] + redB[t][1] + redB[t][2] + redB[t][3];
    float hn = fmaxf(sqrtf(th), 1e-6f);
    float nn = fmaxf(sqrtf(tn), 1e-12f);
    scl[t] = hn / nn;
  }
  __syncthreads();
#pragma unroll
  for (int i = 0; i < 4; i++) {
    int r = q * 4 + i;
    size_t grow = (size_t)(r0 + r);
    float sc = scl[r];
#pragma unroll
    for (int nt = 0; nt < 4; nt++) {
      int c = wave * 64 + nt * 16 + mrow;
      out[grow * MEM + c] = acc[nt][i] * sc;
    }
  }
}

extern "C" void kernel_launch(void* const* d_in, const int* in_sizes, int n_in,
                              void* d_out, int out_size, void* d_ws, size_t ws_size,
                              hipStream_t stream) {
  const float* x   = (const float*)d_in[0];
  const float* h   = (const float*)d_in[1];
  const float* W1  = (const float*)d_in[2];
  const float* b1  = (const float*)d_in[3];
  const float* g1  = (const float*)d_in[4];
  const float* be1 = (const float*)d_in[5];
  const float* W2  = (const float*)d_in[6];
  const float* b2  = (const float*)d_in[7];
  const float* Wd  = (const float*)d_in[8];
  const float* bd  = (const float*)d_in[9];
  const float* Wu  = (const float*)d_in[10];
  const float* bu  = (const float*)d_in[11];
  float* out = (float*)d_out;

  // workspace: WT 8,912,896 | W2T 262,144 | G0 16,777,216 | G1 16,777,216 | Abf 71,303,168
  char* ws = (char*)d_ws;
  u16* WT  = (u16*)(ws);
  u16* W2T = (u16*)(ws + 8912896);
  u16* G0  = (u16*)(ws + 9175040);
  u16* G1  = (u16*)(ws + 25952256);
  u16* Abf = (u16*)(ws + 42729472);

  const int nparts = (ws_size >= 42729472u) ? 2 : 1;
  const int klen = D_IN / nparts;
  const bool use_pre = (ws_size >= 114032640u);  // Abf fits

  transpose_cast_fused<<<dim3(N1 / 64, D_IN / 64), 256, 0, stream>>>(W1, Wd, Wu, WT);
  transpose_cast<<<dim3(256 / 32, 512 / 32), dim3(32, 8), 0, stream>>>(W2, W2T, 512, 256);

  if (use_pre) {
    cast_A_kernel<<<17408, 256, 0, stream>>>(h, x, Abf);
    gemm1_pre_kernel<<<512 * nparts, 256, 0, stream>>>(Abf, WT, G0, G1, klen);
  } else {
    gemm1_inline_kernel<<<512 * nparts, 256, 0, stream>>>(x, h, WT, G0, G1, klen);
  }

  fused_ln_gemm2_kernel<<<B_ROWS / 16, 256, 0, stream>>>(G0, G1, W2T, h, b1, g1, be1,
                                                         b2, bd, bu, out, nparts);
}

// Round 7
// 337.415 us; speedup vs baseline: 1.3657x; 1.0170x over previous
//
#include <hip/hip_runtime.h>
#include <stdint.h>

typedef unsigned short u16;

#define B_ROWS 8192
#define IN_DIM 4096
#define MEM 256
#define D_IN 4352   // MEM + IN_DIM
#define N1 1024     // 512 | 256 | 256
#define K2 512
#define LN_EPS 1e-5f

typedef __attribute__((ext_vector_type(4))) float f32x4;
typedef __attribute__((ext_vector_type(4))) uint32_t u32x4;
typedef __attribute__((ext_vector_type(4))) unsigned short u16x4;
typedef __attribute__((ext_vector_type(8))) short bf16x8;  // 8 bf16 in 4 VGPRs

#define AS1(p) ((__attribute__((address_space(1))) void*)(p))
#define AS3(p) ((__attribute__((address_space(3))) void*)(p))

__device__ __forceinline__ float bf2f(u16 u) {
  union { uint32_t u; float f; } c; c.u = ((uint32_t)u) << 16; return c.f;
}
__device__ __forceinline__ u16 f2bf(float f) {  // round-to-nearest-even
  union { float f; uint32_t u; } c; c.f = f;
  uint32_t r = (c.u + 0x7fffu + ((c.u >> 16) & 1u)) >> 16;
  return (u16)r;
}
__device__ __forceinline__ uint32_t fbits(float f) {
  union { float f; uint32_t u; } c; c.f = f; return c.u;
}
__device__ __forceinline__ uint32_t pack_rne(float a, float b) {
  return ((uint32_t)f2bf(b) << 16) | f2bf(a);
}
__device__ __forceinline__ uint32_t pack_trunc(float a, float b) {
  return (fbits(b) & 0xFFFF0000u) | (fbits(a) >> 16);
}

// -------- merged prep: WT transpose (blocks 0..1087), W2F permute (1088..1103),
//          A cast (1104..18511) --------
__global__ __launch_bounds__(256)
void prep_kernel(const float* __restrict__ W1, const float* __restrict__ Wd,
                 const float* __restrict__ Wu, const float* __restrict__ W2,
                 const float* __restrict__ h, const float* __restrict__ x,
                 u16* __restrict__ WT, u16* __restrict__ W2F, u16* __restrict__ Abf) {
  __shared__ u16 tile[64][68];
  const int blk = blockIdx.x, t = threadIdx.x;
  if (blk < 1088) {
    // ---- {W1,Wd,Wu}[K][*] fp32 -> WT[1024][4352] bf16 (64x64 tiles) ----
    int n0 = (blk & 15) * 64, k0 = (blk >> 4) * 64;
    const float* src; int srcN, ns0;
    if (n0 < 512)      { src = W1; srcN = 512; ns0 = n0; }
    else if (n0 < 768) { src = Wd; srcN = 256; ns0 = n0 - 512; }
    else               { src = Wu; srcN = 256; ns0 = n0 - 768; }
    int rr = t >> 4;        // 0..15
    int c4 = (t & 15) * 4;  // 0..60
#pragma unroll
    for (int i = 0; i < 4; i++) {
      int k = i * 16 + rr;
      f32x4 v = *(const f32x4*)&src[(size_t)(k0 + k) * srcN + ns0 + c4];
      tile[c4 + 0][k] = f2bf(v[0]);
      tile[c4 + 1][k] = f2bf(v[1]);
      tile[c4 + 2][k] = f2bf(v[2]);
      tile[c4 + 3][k] = f2bf(v[3]);
    }
    __syncthreads();
#pragma unroll
    for (int i = 0; i < 4; i++) {
      int n = i * 16 + rr;
      u16x4 w;
      w.x = tile[n][c4 + 0];
      w.y = tile[n][c4 + 1];
      w.z = tile[n][c4 + 2];
      w.w = tile[n][c4 + 3];
      *(u16x4*)&WT[(size_t)(n0 + n) * D_IN + k0 + c4] = w;
    }
  } else if (blk < 1104) {
    // ---- W2[512][256] fp32 -> W2F fragment-major bf16:
    //      W2F[((kw*4+q)*256 + n)*8 + j] = bf16(W2[kw*32+q*8+j][n]) ----
    int kw = blk - 1088;
#pragma unroll
    for (int q = 0; q < 4; q++) {
      float v[8];
#pragma unroll
      for (int j = 0; j < 8; j++)
        v[j] = W2[(size_t)(kw * 32 + q * 8 + j) * 256 + t];
      u32x4 w;
      w.x = pack_rne(v[0], v[1]);
      w.y = pack_rne(v[2], v[3]);
      w.z = pack_rne(v[4], v[5]);
      w.w = pack_rne(v[6], v[7]);
      *(u32x4*)&W2F[(size_t)((kw * 4 + q) * 256 + t) * 8] = w;
    }
  } else {
    // ---- [h|x] fp32 -> Abf bf16 [8192][4352], 8 elems/thread ----
    int b = blk - 1104;
    const float* src; int r, dcol;
    if (b < 1024) {
      int g = (b * 256 + t) * 8;
      src = h + g; r = g >> 8; dcol = g & 255;
    } else {
      int g = ((b - 1024) * 256 + t) * 8;
      src = x + g; r = g >> 12; dcol = MEM + (g & 4095);
    }
    f32x4 v0 = *(const f32x4*)src;
    f32x4 v1 = *(const f32x4*)(src + 4);
    u32x4 w;
    w.x = pack_rne(v0[0], v0[1]);
    w.y = pack_rne(v0[2], v0[3]);
    w.z = pack_rne(v1[0], v1[1]);
    w.w = pack_rne(v1[2], v1[3]);
    *(u32x4*)&Abf[(size_t)r * D_IN + dcol] = w;
  }
}

// -------- GEMM1 (pre-cast A): Abf(bf16) @ WT^T(bf16) -> Gpart bf16 --------
// m97 structure: both operands via global_load_lds width=16. 128x128, BK=64, split-K.
__global__ __launch_bounds__(256, 4)
void gemm1_pre_kernel(const u16* __restrict__ Abf, const u16* __restrict__ WT,
                      u16* __restrict__ G0, u16* __restrict__ G1, int klen) {
  __shared__ __attribute__((aligned(16))) u16 As[128 * 64];
  __shared__ __attribute__((aligned(16))) u16 Bs[128 * 64];
  const int t = threadIdx.x;
  const int lane = t & 63, wave = t >> 6;
  const int by = blockIdx.x & 63;         // M tile (64)
  const int bx = (blockIdx.x >> 6) & 7;   // N tile (8)
  const int part = blockIdx.x >> 9;       // K part
  const int kbase = part * klen;
  u16* __restrict__ Gout = part ? G1 : G0;
  const int row0 = by * 128, col0 = bx * 128;
  const int q = lane >> 4, mrow = lane & 15;
  const int wm = wave >> 1, wn = wave & 1;

  int ar[4], ac[4];
#pragma unroll
  for (int j = 0; j < 4; j++) {
    int idx = j * 256 + t;
    int r = idx >> 3;
    ar[j] = r;
    ac[j] = (idx & 7) ^ (r & 7);
  }

  f32x4 acc[4][4] = {};

  for (int k0 = kbase; k0 < kbase + klen; k0 += 64) {
#pragma unroll
    for (int j = 0; j < 4; j++) {
      const u16* gp = WT + (size_t)(col0 + ar[j]) * D_IN + k0 + ac[j] * 8;
      __builtin_amdgcn_global_load_lds(AS1(gp), AS3(&Bs[(j * 256 + t) * 8]), 16, 0, 0);
    }
#pragma unroll
    for (int j = 0; j < 4; j++) {
      const u16* gp = Abf + (size_t)(row0 + ar[j]) * D_IN + k0 + ac[j] * 8;
      __builtin_amdgcn_global_load_lds(AS1(gp), AS3(&As[(j * 256 + t) * 8]), 16, 0, 0);
    }
    __syncthreads();
#pragma unroll
    for (int kk = 0; kk < 2; kk++) {
      bf16x8 a[4], b[4];
#pragma unroll
      for (int mt = 0; mt < 4; mt++) {
        int row = wm * 64 + mt * 16 + mrow;
        int p = (kk * 4 + q) ^ (mrow & 7);
        a[mt] = *(const bf16x8*)&As[row * 64 + p * 8];
      }
#pragma unroll
      for (int nt = 0; nt < 4; nt++) {
        int row = wn * 64 + nt * 16 + mrow;
        int p = (kk * 4 + q) ^ (mrow & 7);
        b[nt] = *(const bf16x8*)&Bs[row * 64 + p * 8];
      }
#pragma unroll
      for (int mt = 0; mt < 4; mt++) {
#pragma unroll
        for (int nt = 0; nt < 4; nt++) {
          acc[mt][nt] = __builtin_amdgcn_mfma_f32_16x16x32_bf16(a[mt], b[nt], acc[mt][nt], 0, 0, 0);
        }
      }
    }
    __syncthreads();
  }
#pragma unroll
  for (int mt = 0; mt < 4; mt++) {
#pragma unroll
    for (int nt = 0; nt < 4; nt++) {
#pragma unroll
      for (int i = 0; i < 4; i++) {
        int row = row0 + wm * 64 + mt * 16 + q * 4 + i;
        int col = col0 + wn * 64 + nt * 16 + mrow;
        Gout[(size_t)row * N1 + col] = f2bf(acc[mt][nt][i]);
      }
    }
  }
}

// -------- fallback GEMM1 (inline fp32->bf16 A staging) --------
__global__ __launch_bounds__(256, 4)
void gemm1_inline_kernel(const float* __restrict__ x, const float* __restrict__ h,
                         const u16* __restrict__ WT, u16* __restrict__ G0,
                         u16* __restrict__ G1, int klen) {
  __shared__ __attribute__((aligned(16))) u16 As[128 * 64];
  __shared__ __attribute__((aligned(16))) u16 Bs[128 * 64];
  const int t = threadIdx.x;
  const int lane = t & 63, wave = t >> 6;
  const int by = blockIdx.x & 63;
  const int bx = (blockIdx.x >> 6) & 7;
  const int part = blockIdx.x >> 9;
  const int kbase = part * klen;
  u16* __restrict__ Gout = part ? G1 : G0;
  const int row0 = by * 128, col0 = bx * 128;
  const int q = lane >> 4, mrow = lane & 15;
  const int wm = wave >> 1, wn = wave & 1;

  int ar[4], ac[4];
#pragma unroll
  for (int j = 0; j < 4; j++) {
    int idx = j * 256 + t;
    int r = idx >> 3;
    ar[j] = r;
    ac[j] = (idx & 7) ^ (r & 7);
  }
  f32x4 acc[4][4] = {};
  for (int k0 = kbase; k0 < kbase + klen; k0 += 64) {
#pragma unroll
    for (int j = 0; j < 4; j++) {
      const u16* gp = WT + (size_t)(col0 + ar[j]) * D_IN + k0 + ac[j] * 8;
      __builtin_amdgcn_global_load_lds(AS1(gp), AS3(&Bs[(j * 256 + t) * 8]), 16, 0, 0);
    }
#pragma unroll
    for (int j = 0; j < 4; j++) {
      int k = k0 + ac[j] * 8;
      const float* gp = (k < MEM) ? (h + (size_t)(row0 + ar[j]) * MEM + k)
                                  : (x + (size_t)(row0 + ar[j]) * IN_DIM + (k - MEM));
      f32x4 v0 = *(const f32x4*)gp;
      f32x4 v1 = *(const f32x4*)(gp + 4);
      u32x4 w;
      w.x = pack_trunc(v0[0], v0[1]);
      w.y = pack_trunc(v0[2], v0[3]);
      w.z = pack_trunc(v1[0], v1[1]);
      w.w = pack_trunc(v1[2], v1[3]);
      *(u32x4*)&As[(j * 256 + t) * 8] = w;
    }
    __syncthreads();
#pragma unroll
    for (int kk = 0; kk < 2; kk++) {
      bf16x8 a[4], b[4];
#pragma unroll
      for (int mt = 0; mt < 4; mt++) {
        int row = wm * 64 + mt * 16 + mrow;
        int p = (kk * 4 + q) ^ (mrow & 7);
        a[mt] = *(const bf16x8*)&As[row * 64 + p * 8];
      }
#pragma unroll
      for (int nt = 0; nt < 4; nt++) {
        int row = wn * 64 + nt * 16 + mrow;
        int p = (kk * 4 + q) ^ (mrow & 7);
        b[nt] = *(const bf16x8*)&Bs[row * 64 + p * 8];
      }
#pragma unroll
      for (int mt = 0; mt < 4; mt++) {
#pragma unroll
        for (int nt = 0; nt < 4; nt++) {
          acc[mt][nt] = __builtin_amdgcn_mfma_f32_16x16x32_bf16(a[mt], b[nt], acc[mt][nt], 0, 0, 0);
        }
      }
    }
    __syncthreads();
  }
#pragma unroll
  for (int mt = 0; mt < 4; mt++) {
#pragma unroll
    for (int nt = 0; nt < 4; nt++) {
#pragma unroll
      for (int i = 0; i < 4; i++) {
        int row = row0 + wm * 64 + mt * 16 + q * 4 + i;
        int col = col0 + wn * 64 + nt * 16 + mrow;
        Gout[(size_t)row * N1 + col] = f2bf(acc[mt][nt][i]);
      }
    }
  }
}

// -------- fused LN+GELU+GEMM2+epilogue -> out fp32 [8192][256] --------
// 16-row tiles, grid 512. Phase 1: LN+GELU into LDS As. Phase 2: barrier-free
// K-loop — A from LDS, B direct global (fragment-major W2F, L2-resident).
// Phase 3: gates + blend + row-norm rescale.
__global__ __launch_bounds__(256, 4)
void fused_ln_gemm2_kernel(const u16* __restrict__ G0, const u16* __restrict__ G1,
                           const u16* __restrict__ W2F, const float* __restrict__ h,
                           const float* __restrict__ b1v, const float* __restrict__ g1v,
                           const float* __restrict__ be1v, const float* __restrict__ b2,
                           const float* __restrict__ bd, const float* __restrict__ bu,
                           float* __restrict__ out, int nparts) {
  __shared__ __attribute__((aligned(16))) u16 As[16 * 512];   // 16 KB
  __shared__ float redA[16][4], redB[16][4], scl[16];
  const int t = threadIdx.x, lane = t & 63, wave = t >> 6;
  const int q = lane >> 4, mrow = lane & 15;
  const int r0 = blockIdx.x * 16;

  // ---- Phase 1: LN + exact GELU ----
  {
    const int lr = t & 15;   // row in tile
    const int lc = t >> 4;   // 32-col chunk [0,16)
    float z[32];
    const u16* g0p = G0 + (size_t)(r0 + lr) * N1 + lc * 32;
    const u16* g1p = G1 + (size_t)(r0 + lr) * N1 + lc * 32;
    float s = 0.f, ss = 0.f;
#pragma unroll
    for (int j = 0; j < 4; j++) {
      u32x4 w0 = *(const u32x4*)(g0p + j * 8);
      u32x4 w1;
      if (nparts == 2) w1 = *(const u32x4*)(g1p + j * 8);
#pragma unroll
      for (int e = 0; e < 4; e++) {
        float lo = bf2f((u16)(w0[e] & 0xffff));
        float hi = bf2f((u16)(w0[e] >> 16));
        if (nparts == 2) {
          lo += bf2f((u16)(w1[e] & 0xffff));
          hi += bf2f((u16)(w1[e] >> 16));
        }
        int cb = lc * 32 + j * 8 + e * 2;
        lo += b1v[cb];
        hi += b1v[cb + 1];
        z[j * 8 + e * 2] = lo;
        z[j * 8 + e * 2 + 1] = hi;
        s += lo + hi;
        ss += lo * lo + hi * hi;
      }
    }
    s += __shfl_xor(s, 16, 64);  s += __shfl_xor(s, 32, 64);
    ss += __shfl_xor(ss, 16, 64); ss += __shfl_xor(ss, 32, 64);
    if (lane < 16) { redA[lr][wave] = s; redB[lr][wave] = ss; }
    __syncthreads();
    float S  = redA[lr][0] + redA[lr][1] + redA[lr][2] + redA[lr][3];
    float SS = redB[lr][0] + redB[lr][1] + redB[lr][2] + redB[lr][3];
    float mu = S * (1.0f / 512.0f);
    float var = SS * (1.0f / 512.0f) - mu * mu;
    float rstd = rsqrtf(var + LN_EPS);
#pragma unroll
    for (int j = 0; j < 4; j++) {
      u32x4 wpk;
#pragma unroll
      for (int e = 0; e < 4; e++) {
        int cb = lc * 32 + j * 8 + e * 2;
        float y0 = (z[j * 8 + e * 2] - mu) * rstd * g1v[cb] + be1v[cb];
        float y1 = (z[j * 8 + e * 2 + 1] - mu) * rstd * g1v[cb + 1] + be1v[cb + 1];
        float o0 = 0.5f * y0 * (1.0f + erff(y0 * 0.7071067811865475f));
        float o1 = 0.5f * y1 * (1.0f + erff(y1 * 0.7071067811865475f));
        wpk[e] = pack_rne(o0, o1);
      }
      int p = lc * 4 + j;            // chunk index [0,64)
      int ps = p ^ (lr & 7);
      *(u32x4*)&As[lr * 512 + ps * 8] = wpk;
    }
  }
  __syncthreads();  // As visible to all waves

  // ---- Phase 2: barrier-free GEMM. B streams global->VGPR from W2F (L2-hot) ----
  f32x4 acc[4] = {};
#pragma unroll
  for (int kw = 0; kw < 16; kw++) {
    int pa = (kw * 4 + q) ^ (mrow & 7);
    bf16x8 a = *(const bf16x8*)&As[mrow * 512 + pa * 8];
#pragma unroll
    for (int nt = 0; nt < 4; nt++) {
      const u16* bp = W2F + (size_t)((kw * 4 + q) * 256 + wave * 64 + nt * 16 + mrow) * 8;
      bf16x8 b = *(const bf16x8*)bp;
      acc[nt] = __builtin_amdgcn_mfma_f32_16x16x32_bf16(a, b, acc[nt], 0, 0, 0);
    }
  }
  __syncthreads();  // before redA/redB reuse

  // ---- Phase 3: gates + blend + row-norm rescale ----
  float snh[4], shh[4];
#pragma unroll
  for (int i = 0; i < 4; i++) {
    int r = q * 4 + i;
    size_t grow = (size_t)(r0 + r);
    float a_nh = 0.f, a_h = 0.f;
#pragma unroll
    for (int nt = 0; nt < 4; nt++) {
      int c = wave * 64 + nt * 16 + mrow;
      float hc = tanhf(acc[nt][i] + b2[c]);
      float zd = bf2f(G0[grow * N1 + 512 + c]);
      float zu = bf2f(G0[grow * N1 + 768 + c]);
      if (nparts == 2) {
        zd += bf2f(G1[grow * N1 + 512 + c]);
        zu += bf2f(G1[grow * N1 + 768 + c]);
      }
      zd += bd[c];
      zu += bu[c];
      float dec = 0.1f + 9.9f / (1.0f + expf(-zd)) + 1e-6f;
      float u = 1.0f / (1.0f + expf(-zu));
      float hv = h[grow * MEM + c];
      float nh = (1.0f - u) * (hv / dec) + u * hc;
      acc[nt][i] = nh;
      a_nh += nh * nh;
      a_h += hv * hv;
    }
    snh[i] = a_nh;
    shh[i] = a_h;
  }
#pragma unroll
  for (int m = 1; m <= 8; m <<= 1) {
#pragma unroll
    for (int i = 0; i < 4; i++) {
      snh[i] += __shfl_xor(snh[i], m, 64);
      shh[i] += __shfl_xor(shh[i], m, 64);
    }
  }
  if (mrow == 0) {
#pragma unroll
    for (int i = 0; i < 4; i++) {
      int r = q * 4 + i;
      redA[r][wave] = snh[i];
      redB[r][wave] = shh[i];
    }
  }
  __syncthreads();
  if (t < 16) {
    float tn = redA[t][0] + redA[t][1] + redA[t][2] + redA[t][3];
    float th = redB[t][0] + redB[t][1] + redB[t][2] + redB[t][3];
    float hn = fmaxf(sqrtf(th), 1e-6f);
    float nn = fmaxf(sqrtf(tn), 1e-12f);
    scl[t] = hn / nn;
  }
  __syncthreads();
#pragma unroll
  for (int i = 0; i < 4; i++) {
    int r = q * 4 + i;
    size_t grow = (size_t)(r0 + r);
    float sc = scl[r];
#pragma unroll
    for (int nt = 0; nt < 4; nt++) {
      int c = wave * 64 + nt * 16 + mrow;
      out[grow * MEM + c] = acc[nt][i] * sc;
    }
  }
}

extern "C" void kernel_launch(void* const* d_in, const int* in_sizes, int n_in,
                              void* d_out, int out_size, void* d_ws, size_t ws_size,
                              hipStream_t stream) {
  const float* x   = (const float*)d_in[0];
  const float* h   = (const float*)d_in[1];
  const float* W1  = (const float*)d_in[2];
  const float* b1  = (const float*)d_in[3];
  const float* g1  = (const float*)d_in[4];
  const float* be1 = (const float*)d_in[5];
  const float* W2  = (const float*)d_in[6];
  const float* b2  = (const float*)d_in[7];
  const float* Wd  = (const float*)d_in[8];
  const float* bd  = (const float*)d_in[9];
  const float* Wu  = (const float*)d_in[10];
  const float* bu  = (const float*)d_in[11];
  float* out = (float*)d_out;

  // workspace: WT 8,912,896 | W2F 262,144 | G0 16,777,216 | G1 16,777,216 | Abf 71,303,168
  char* ws = (char*)d_ws;
  u16* WT  = (u16*)(ws);
  u16* W2F = (u16*)(ws + 8912896);
  u16* G0  = (u16*)(ws + 9175040);
  u16* G1  = (u16*)(ws + 25952256);
  u16* Abf = (u16*)(ws + 42729472);

  const int nparts = (ws_size >= 42729472u) ? 2 : 1;
  const int klen = D_IN / nparts;
  const bool use_pre = (ws_size >= 114032640u);  // Abf fits (confirmed active in r6)

  if (use_pre) {
    prep_kernel<<<18512, 256, 0, stream>>>(W1, Wd, Wu, W2, h, x, WT, W2F, Abf);
    gemm1_pre_kernel<<<512 * nparts, 256, 0, stream>>>(Abf, WT, G0, G1, klen);
  } else {
    prep_kernel<<<1104, 256, 0, stream>>>(W1, Wd, Wu, W2, h, x, WT, W2F, Abf);
    gemm1_inline_kernel<<<512 * nparts, 256, 0, stream>>>(x, h, WT, G0, G1, klen);
  }

  fused_ln_gemm2_kernel<<<B_ROWS / 16, 256, 0, stream>>>(G0, G1, W2F, h, b1, g1, be1,
                                                         b2, bd, bu, out, nparts);
}